// Round 1
// 195.610 us; speedup vs baseline: 1.1273x; 1.1273x over previous
//
#include <hip/hip_runtime.h>

// Kalman filter, BATCH=256, SEQ=4096, N=16, M=8, U=4.
// Riccati gain converges (rho((I-KC)A) ~ 0.2 per step on P) -> 8 exact steps
// then frozen steady gain. Chunked parallel scan over the affine recurrence
// x' = G x + K z + Bf u with 32-step chunks:
//   k_riccati: 8 exact steps (in-register shfl Gauss-Jordan for S^-1, 6
//              barriers/step), steady mats, H = G^32 by squaring.
//   k_phase1:  chunk j response from zero (chunk 0: true trajectory from x0,
//              8 exact + 24 steady steps, writes out t=0..32). 2048 blocks.
//   k_scan:    serial chunk-level scan xs_{j+1} = H xs_j + d_j, in-place in
//              the d-slot buffer. 14-deep register prefetch ring so the
//              remote-XCD/HBM d_j loads are pipelined (was 1-deep: each of
//              126 steps exposed ~900cy latency -> 45.7us; now VALU-bound).
//   k_phase3:  chunks 1..127 replay from true start states, write out.
// Phases: 4 lanes/batch, x broadcast via DPP quad-perm (VALU pipe, no LDS,
// no barriers), matrices in VGPRs, z/u as register-prefetched float4 loads.

#define SEQ_T  4096
#define NSTEP  4095
#define NB     256
#define NEX    8
#define LCH    32
#define NCHT   128   // chunks 0..127; chunk j covers steps j*32 .. j*32+31 (<4095)

// workspace layout (float offsets); slot j of DB holds d_j, overwritten by
// k_scan with xs_{j+1} (start state of chunk j+1). slot 0 stays d_0 = xs_1.
#define EX_OFF 0
#define ST_OFF (NEX*448)
#define HI_OFF (ST_OFF+448)
#define DB_OFF (HI_OFF+256)
// total = 8*448 + 448 + 256 + 128*4096 = 528,672 floats ~ 2.1 MB

// ---------------------------------------------------------------- DPP util
template<int KQ>
__device__ __forceinline__ void bc4(const float* xr, float* xk) {
#pragma unroll
  for (int r = 0; r < 4; r++)
    xk[r] = __int_as_float(__builtin_amdgcn_update_dpp(
        0, __float_as_int(xr[r]), KQ * 0x55, 0xF, 0xF, true));
}

// ---------------------------------------------------------------- k_riccati
__global__ __launch_bounds__(64) void k_riccati(
    const float* __restrict__ Ag, const float* __restrict__ Bg,
    const float* __restrict__ Cg, const float* __restrict__ Qg,
    const float* __restrict__ Rg, float* __restrict__ ws)
{
  const int l = threadIdx.x;
  __shared__ float As[256], Qs[256], Cs[128], Bs[64], CA[128], CB[32];
  __shared__ float Pp[256], Vv[128], Km[128], Gm[256], T1[256], T2[256], Xs[64];

#pragma unroll
  for (int j=0;j<4;j++){ int e=l+64*j; As[e]=Ag[e]; Qs[e]=Qg[e]; }
  Cs[l]=Cg[l]; Cs[l+64]=Cg[l+64];
  Bs[l]=Bg[l];
  const float rr = Rg[l];
  __syncthreads();

  const int r4=l>>2, g4=l&3;   // (row, col-group) for 16x16 work
  const int r8=l>>3, c8=l&7;   // (row, col) for 8-wide work

  // CA = C*A (8x16), CB = C*B (8x4), Pp0 = A*A^T + Q
  { int e=l; { int r=e>>4,c=e&15; float a=0.f;
      for (int k=0;k<16;k++) a+=Cs[r*16+k]*As[k*16+c]; CA[e]=a; }
    e=l+64; { int r=e>>4,c=e&15; float a=0.f;
      for (int k=0;k<16;k++) a+=Cs[r*16+k]*As[k*16+c]; CA[e]=a; }
    if (l<32){ int r=l>>2,c=l&3; float a=0.f;
      for (int k=0;k<16;k++) a+=Cs[r*16+k]*Bs[k*4+c]; CB[l]=a; }
#pragma unroll
    for (int j=0;j<4;j++){ int c=4*g4+j; float a=Qs[r4*16+c];
      for (int k=0;k<16;k++) a+=As[r4*16+k]*As[c*16+k]; Pp[r4*16+c]=a; }
  }
  __syncthreads();

  float kv0=0.f, kv1=0.f, bfv=0.f;
  for (int s=0;s<NEX;s++){
    // V = P_pri * C^T (16x8), 2 elems/lane
    { int e=l; { int r=e>>3,c=e&7; float a=0.f;
        for (int k=0;k<16;k++) a+=Pp[r*16+k]*Cs[c*16+k]; Vv[e]=a; }
      e=l+64; { int r=e>>3,c=e&7; float a=0.f;
        for (int k=0;k<16;k++) a+=Pp[r*16+k]*Cs[c*16+k]; Vv[e]=a; } }
    __syncthreads();
    // S = C*V + R, then in-register Gauss-Jordan via shfl (no barriers)
    { float sv=rr;
      for (int k=0;k<16;k++) sv += Cs[r8*16+k]*Vv[k*8+c8];
      float xv = (r8==c8)?1.f:0.f;
#pragma unroll
      for (int p=0;p<8;p++){
        float spp = __shfl(sv, p*9);
        float pr  = 1.0f/spp;
        float spc = __shfl(sv, p*8+c8);
        float xpc = __shfl(xv, p*8+c8);
        float srp = __shfl(sv, r8*8+p);
        float f = srp*pr;
        if (r8==p){ sv = spc*pr; xv = xpc*pr; }
        else      { sv -= f*spc; xv -= f*xpc; }
      }
      Xs[l]=xv; }
    __syncthreads();
    // K = V * S^-1 (16x8), 2 elems/lane; keep in regs for emit
    { int e=l; { int r=e>>3,c=e&7; float a=0.f;
        for (int k=0;k<8;k++) a+=Vv[r*8+k]*Xs[k*8+c]; kv0=a; Km[e]=a; }
      e=l+64; { int r=e>>3,c=e&7; float a=0.f;
        for (int k=0;k<8;k++) a+=Vv[r*8+k]*Xs[k*8+c]; kv1=a; Km[e]=a; } }
    __syncthreads();
    // G = A - K*CA ; W = P - K*V^T (in place over Pp) ; Bf = B - K*CB ; emit
    { float gv[4];
#pragma unroll
      for (int j=0;j<4;j++){ int c=4*g4+j;
        float a=As[r4*16+c], w=Pp[r4*16+c];
        for (int k=0;k<8;k++){ a -= Km[r4*8+k]*CA[k*16+c]; w -= Km[r4*8+k]*Vv[c*8+k]; }
        gv[j]=a; Gm[r4*16+c]=a; Pp[r4*16+c]=w; }
      bfv = Bs[l];
      for (int k=0;k<8;k++) bfv -= Km[r4*8+k]*CB[k*4+g4];
      float* dst = ws + EX_OFF + s*448;
      *reinterpret_cast<float4*>(dst + r4*16 + g4*4) =
          make_float4(gv[0],gv[1],gv[2],gv[3]);
      dst[256+l]=kv0; dst[256+64+l]=kv1; dst[384+l]=bfv;
    }
    __syncthreads();
    // T1 = A * W
#pragma unroll
    for (int j=0;j<4;j++){ int c=4*g4+j; float a=0.f;
      for (int k=0;k<16;k++) a+=As[r4*16+k]*Pp[k*16+c]; T1[r4*16+c]=a; }
    __syncthreads();
    // P_pri' = T1 * A^T + Q
#pragma unroll
    for (int j=0;j<4;j++){ int c=4*g4+j; float a=Qs[r4*16+c];
      for (int k=0;k<16;k++) a+=T1[r4*16+k]*As[c*16+k]; Pp[r4*16+c]=a; }
    __syncthreads();
  }
  // steady mats = last step's (converged)
  { float* dst = ws + ST_OFF;
    *reinterpret_cast<float4*>(dst + r4*16 + g4*4) =
        *reinterpret_cast<float4*>(&Gm[r4*16 + g4*4]);
    dst[256+l]=kv0; dst[256+64+l]=kv1; dst[384+l]=bfv; }
  // HI = G^32 by 5 squarings
#pragma unroll
  for (int j=0;j<4;j++) T1[l+64*j]=Gm[l+64*j];
  __syncthreads();
  for (int it=0; it<5; it++){
#pragma unroll
    for (int j=0;j<4;j++){ int c=4*g4+j; float a=0.f;
      for (int k=0;k<16;k++) a+=T1[r4*16+k]*T1[k*16+c]; T2[r4*16+c]=a; }
    __syncthreads();
#pragma unroll
    for (int j=0;j<4;j++) T1[l+64*j]=T2[l+64*j];
    __syncthreads();
  }
#pragma unroll
  for (int j=0;j<4;j++) ws[HI_OFF + l+64*j] = T1[l+64*j];
}

// ---------------------------------------------------------- phase mat load
__device__ __forceinline__ void ld_rows(const float* __restrict__ m, int q,
    float gm[4][16], float km[4][8], float bf[4][4]) {
#pragma unroll
  for (int r=0;r<4;r++){
    const int row = 4*q + r;
    const float4* gp = reinterpret_cast<const float4*>(m + row*16);
#pragma unroll
    for (int kk=0;kk<4;kk++){ float4 t=gp[kk];
      gm[r][4*kk]=t.x; gm[r][4*kk+1]=t.y; gm[r][4*kk+2]=t.z; gm[r][4*kk+3]=t.w; }
    const float4* kp = reinterpret_cast<const float4*>(m + 256 + row*8);
#pragma unroll
    for (int kk=0;kk<2;kk++){ float4 t=kp[kk];
      km[r][4*kk]=t.x; km[r][4*kk+1]=t.y; km[r][4*kk+2]=t.z; km[r][4*kk+3]=t.w; }
    float4 t = *reinterpret_cast<const float4*>(m + 384 + row*4);
    bf[r][0]=t.x; bf[r][1]=t.y; bf[r][2]=t.z; bf[r][3]=t.w;
  }
}

// MODE 0: phase1 steady chunk (from zero, write d_j)
// MODE 1: phase1 chunk 0 (exact+steady from x0, write out t=0..32 and d_0)
// MODE 2: phase3 (steady, from true start state, write out)
template<int MODE>
__device__ __forceinline__ void chunk_run(
    const float* __restrict__ obs, const float* __restrict__ inp,
    const float* __restrict__ x0g, float* __restrict__ ws,
    float* __restrict__ out, int j, int g)
{
  const int l=threadIdx.x, bl=l>>2, q=l&3, b=g*16+bl;
  const int s0 = j*LCH;
  const int nst = (NSTEP - s0 < LCH) ? (NSTEP - s0) : LCH;

  float gm[4][16], km[4][8], bf[4][4];
  if (MODE==1) ld_rows(ws + EX_OFF, q, gm, km, bf);
  else         ld_rows(ws + ST_OFF, q, gm, km, bf);

  float xr[4];
  if (MODE==0){ xr[0]=xr[1]=xr[2]=xr[3]=0.f; }
  else if (MODE==1){
    float4 x = *reinterpret_cast<const float4*>(x0g + q*4);
    xr[0]=x.x; xr[1]=x.y; xr[2]=x.z; xr[3]=x.w;
    *reinterpret_cast<float4*>(out + (size_t)b*(SEQ_T*16) + q*4) = x;  // t=0
  } else {
    float4 x = *reinterpret_cast<const float4*>(
        ws + DB_OFF + (size_t)(j-1)*(NB*16) + b*16 + q*4);
    xr[0]=x.x; xr[1]=x.y; xr[2]=x.z; xr[3]=x.w;
  }

  const float* zp = obs + (size_t)b*(SEQ_T*8);
  const float* up = inp + (size_t)b*(SEQ_T*4);
  float4 z0n = *reinterpret_cast<const float4*>(zp + (size_t)(s0+1)*8);
  float4 z1n = *reinterpret_cast<const float4*>(zp + (size_t)(s0+1)*8 + 4);
  float4 u0n = *reinterpret_cast<const float4*>(up + (size_t)(s0+1)*4);

  for (int st=0; st<nst; st++){
    float4 z0=z0n, z1=z1n, u0=u0n;
    if (st+1 < nst){
      const size_t t = s0+st+2;
      z0n = *reinterpret_cast<const float4*>(zp + t*8);
      z1n = *reinterpret_cast<const float4*>(zp + t*8 + 4);
      u0n = *reinterpret_cast<const float4*>(up + t*4);
    }
    float xk[16];
    bc4<0>(xr, xk); bc4<1>(xr, xk+4); bc4<2>(xr, xk+8); bc4<3>(xr, xk+12);
    float xn[4];
#pragma unroll
    for (int r=0;r<4;r++){
      float a = bf[r][0]*u0.x + bf[r][1]*u0.y + bf[r][2]*u0.z + bf[r][3]*u0.w;
      a += km[r][0]*z0.x + km[r][1]*z0.y + km[r][2]*z0.z + km[r][3]*z0.w;
      a += km[r][4]*z1.x + km[r][5]*z1.y + km[r][6]*z1.z + km[r][7]*z1.w;
#pragma unroll
      for (int k=0;k<16;k++) a += gm[r][k]*xk[k];
      xn[r]=a;
    }
#pragma unroll
    for (int r=0;r<4;r++) xr[r]=xn[r];
    if (MODE>=1)
      *reinterpret_cast<float4*>(out + (size_t)b*(SEQ_T*16) +
                                 (size_t)(s0+st+1)*16 + q*4) =
          make_float4(xr[0],xr[1],xr[2],xr[3]);
    if (MODE==1 && st+1 < nst){
      if (st+1 < NEX)       ld_rows(ws + EX_OFF + (st+1)*448, q, gm, km, bf);
      else if (st+1 == NEX) ld_rows(ws + ST_OFF, q, gm, km, bf);
    }
  }
  if (MODE<=1)
    *reinterpret_cast<float4*>(ws + DB_OFF + (size_t)j*(NB*16) + b*16 + q*4) =
        make_float4(xr[0],xr[1],xr[2],xr[3]);
}

__global__ __launch_bounds__(64,2) void k_phase1(
    const float* __restrict__ obs, const float* __restrict__ inp,
    const float* __restrict__ x0g, float* __restrict__ ws,
    float* __restrict__ out)
{
  const int j = blockIdx.x>>4, g = blockIdx.x&15;
  if (j==0) chunk_run<1>(obs, inp, x0g, ws, out, j, g);
  else      chunk_run<0>(obs, inp, x0g, ws, out, j, g);
}

__global__ __launch_bounds__(64,2) void k_phase3(
    const float* __restrict__ obs, const float* __restrict__ inp,
    float* __restrict__ ws, float* __restrict__ out)
{
  const int j = 1 + (blockIdx.x>>4), g = blockIdx.x&15;
  chunk_run<2>(obs, inp, nullptr, ws, out, j, g);
}

// ------------------------------------------------------------- k_scan
// Serial chunk-level scan, 126 dependent steps. The d_j loads come from
// lines written by k_phase1 on all 8 XCDs -> remote-L2/HBM latency ~900cy.
// 14-deep statically-indexed register ring (126 = 9*14) keeps 14 loads in
// flight: 14 iter x ~170cy compute = ~2400cy between issue and consume,
// fully covering load latency. All ring indices are compile-time constants
// (runtime-indexed float4 arrays would spill to scratch).
__global__ __launch_bounds__(256) void k_scan(float* __restrict__ ws)
{
  const int tid=threadIdx.x, lane=tid&63, wv=tid>>6, bl=lane>>2, q=lane&3;
  const int b = blockIdx.x*64 + wv*16 + bl;
  float hm[4][16];
#pragma unroll
  for (int r=0;r<4;r++){
    const int row = 4*q + r;
    const float4* hp = reinterpret_cast<const float4*>(ws + HI_OFF + row*16);
#pragma unroll
    for (int kk=0;kk<4;kk++){ float4 t=hp[kk];
      hm[r][4*kk]=t.x; hm[r][4*kk+1]=t.y; hm[r][4*kk+2]=t.z; hm[r][4*kk+3]=t.w; }
  }
  float* p = ws + DB_OFF + (size_t)b*16 + q*4;   // slot stride = NB*16 floats
  float4 xi = *reinterpret_cast<const float4*>(p);   // slot 0 = d_0 = xs_1
  float xr[4]={xi.x,xi.y,xi.z,xi.w};

  float4 dbuf[14];
#pragma unroll
  for (int k=0;k<14;k++)
    dbuf[k] = *reinterpret_cast<const float4*>(p + (size_t)(1+k)*(NB*16));

  for (int base=0; base<9; base++){
#pragma unroll
    for (int k=0;k<14;k++){
      const int jj = 1 + base*14 + k;           // 1..126
      float4 d = dbuf[k];
      if (jj+14 <= 126)                          // refill ring 14 ahead
        dbuf[k] = *reinterpret_cast<const float4*>(
            p + (size_t)(jj+14)*(NB*16));
      float xk[16];
      bc4<0>(xr, xk); bc4<1>(xr, xk+4); bc4<2>(xr, xk+8); bc4<3>(xr, xk+12);
      float xn[4]={d.x,d.y,d.z,d.w};
#pragma unroll
      for (int r=0;r<4;r++){
#pragma unroll
        for (int kk=0;kk<16;kk++) xn[r]+=hm[r][kk]*xk[kk];
      }
#pragma unroll
      for (int r=0;r<4;r++) xr[r]=xn[r];
      *reinterpret_cast<float4*>(p + (size_t)jj*(NB*16)) =
          make_float4(xr[0],xr[1],xr[2],xr[3]);   // slot jj := xs_{jj+1}
    }
  }
}

// ------------------------------------------------------------- launcher
extern "C" void kernel_launch(void* const* d_in, const int* in_sizes, int n_in,
                              void* d_out, int out_size, void* d_ws, size_t ws_size,
                              hipStream_t stream) {
  const float* obs = (const float*)d_in[0];
  const float* inp = (const float*)d_in[1];
  const float* A   = (const float*)d_in[2];
  const float* B   = (const float*)d_in[3];
  const float* C   = (const float*)d_in[4];
  const float* Q   = (const float*)d_in[5];
  const float* R   = (const float*)d_in[6];
  const float* x0  = (const float*)d_in[7];
  float* out = (float*)d_out;
  float* ws  = (float*)d_ws;

  k_riccati<<<dim3(1),        dim3(64),  0, stream>>>(A, B, C, Q, R, ws);
  k_phase1 <<<dim3(NCHT*16),  dim3(64),  0, stream>>>(obs, inp, x0, ws, out);
  k_scan   <<<dim3(4),        dim3(256), 0, stream>>>(ws);
  k_phase3 <<<dim3(127*16),   dim3(64),  0, stream>>>(obs, inp, ws, out);
}